// Round 6
// baseline (112.143 us; speedup 1.0000x reference)
//
#include <hip/hip_runtime.h>
#include <hip/hip_bf16.h>

#define TEMP_INV 14.285714285714286f     // 1/0.07
#define KL2E     20.60992947626f         // TEMP_INV * log2(e)
#define NC2      (-20.60992947626f)      // shift so exp2-arg <= 0 (unit-norm rows)
#define NBATCH 16
#define NROWS 2048
#define DDIM 128

typedef __attribute__((ext_vector_type(8))) short bf16x8;
typedef __attribute__((ext_vector_type(4))) float f32x4;

// async global->LDS, 16B per lane; LDS dest = wave-uniform base + lane*16
#define GLOAD16(g, l) \
  __builtin_amdgcn_global_load_lds((const __attribute__((address_space(1))) void*)(g), \
                                   (__attribute__((address_space(3))) void*)(l), 16, 0, 0)

// ---------------- K1: cast fp32 [16,1024,2,128] -> bf16 contrast [16,2048,128]
__global__ __launch_bounds__(256) void cast_reorder_kernel(
    const float* __restrict__ feat, __hip_bfloat16* __restrict__ out)
{
    int t = blockIdx.x * blockDim.x + threadIdx.x;
    int e = t << 2;
    int d = e & 127;
    int v = (e >> 7) & 1;
    int i = (e >> 8) & 1023;
    int b = e >> 18;
    const float4 f = *reinterpret_cast<const float4*>(feat + e);
    union { __hip_bfloat16 h[4]; uint2 u; } o;
    o.h[0] = __float2bfloat16(f.x);
    o.h[1] = __float2bfloat16(f.y);
    o.h[2] = __float2bfloat16(f.z);
    o.h[3] = __float2bfloat16(f.w);
    size_t oe = (size_t)(((b << 11) + (v << 10) + i)) * DDIM + d;
    *reinterpret_cast<uint2*>(out + oe) = o.u;
}

// ---------------- K2: fused Gram + streamlined epilogue
// grid 512 = 16 batches x 32 row-blocks(64). 256 thr (4 waves, 2x2 of 32r x 64c).
__global__ __launch_bounds__(256) void supcon_main_kernel(
    const __hip_bfloat16* __restrict__ contrast,
    const int* __restrict__ labels,
    float* __restrict__ rsum_ws, float* __restrict__ ps_ws, float* __restrict__ sd_ws)
{
    __shared__ __hip_bfloat16 Bt[2][128 * DDIM];   // 64 KB dbuf; Bt[1] doubles as A-buf in prologue
    __shared__ int slab[1024];
    __shared__ float red_se[2][64], red_ps[2][64], red_sd[2][64];

    const int tid  = threadIdx.x;
    const int lane = tid & 63;
    const int w    = tid >> 6;
    const int wrow = w >> 1, wcol = w & 1;

    // XCD-aware remap: each XCD owns 2 whole batches (B-panel fits its L2)
    const int bid = blockIdx.x;
    const int xcd = bid & 7, idx = bid >> 3;
    const int b   = xcd * 2 + (idx >> 5);
    const int rb  = idx & 31;
    const int n0  = rb * 64;

    const __hip_bfloat16* cb = contrast + (size_t)b * NROWS * DDIM;
    const int* lb = labels + b * 1024;

    #pragma unroll
    for (int it = 0; it < 4; ++it) slab[it * 256 + tid] = lb[it * 256 + tid];

    // ---- async-stage A tile (rows n0..n0+63) into Bt[1]; source pre-swizzled (rule #21)
    #pragma unroll
    for (int c = 0; c < 4; ++c) {
        const int r = (c * 4 + w) * 4 + (lane >> 4);
        const int p = lane & 15;
        GLOAD16(cb + (size_t)(n0 + r) * DDIM + ((p ^ (r & 7)) << 3),
                (char*)(&Bt[1][0]) + (c * 4 + w) * 1024);
    }
    // ---- async-stage B tile 0 (rows 0..127) into Bt[0]
    #pragma unroll
    for (int c = 0; c < 8; ++c) {
        const int r = (c * 4 + w) * 4 + (lane >> 4);
        const int p = lane & 15;
        GLOAD16(cb + (size_t)r * DDIM + ((p ^ (r & 7)) << 3),
                (char*)(&Bt[0][0]) + (c * 4 + w) * 1024);
    }
    __syncthreads();   // full drain: staging visible

    // ---- preload A fragments (swizzled reads), then free the A region
    bf16x8 afrag[2][4];
    #pragma unroll
    for (int fr = 0; fr < 2; ++fr) {
        const int arow = wrow * 32 + fr * 16 + (lane & 15);
        #pragma unroll
        for (int ks = 0; ks < 4; ++ks) {
            const int q = ks * 4 + (lane >> 4);
            afrag[fr][ks] = *reinterpret_cast<const bf16x8*>(
                (const char*)(&Bt[1][0]) + arow * 256 + ((q ^ (arow & 7)) << 4));
        }
    }
    int rown[2][4], rowlab[2][4];
    #pragma unroll
    for (int fr = 0; fr < 2; ++fr)
        #pragma unroll
        for (int j = 0; j < 4; ++j) {
            const int n = n0 + wrow * 32 + fr * 16 + ((lane >> 4) << 2) + j;
            rown[fr][j] = n;
            rowlab[fr][j] = slab[n & 1023];
        }
    __syncthreads();   // all waves done reading A region before tile-1 staging overwrites it

    // per-thread staging source pointers for tiles 1..15 (advance 128 rows/tile)
    const __hip_bfloat16* gsrc[8];
    #pragma unroll
    for (int c = 0; c < 8; ++c) {
        const int r = (c * 4 + w) * 4 + (lane >> 4);
        const int p = lane & 15;
        gsrc[c] = cb + (size_t)(128 + r) * DDIM + ((p ^ (r & 7)) << 3);
    }
    // precomputed LDS byte offsets for bfrag reads
    int boff[4][4];
    #pragma unroll
    for (int fc = 0; fc < 4; ++fc) {
        const int brow = wcol * 64 + fc * 16 + (lane & 15);
        #pragma unroll
        for (int ks = 0; ks < 4; ++ks) {
            const int q = ks * 4 + (lane >> 4);
            boff[fc][ks] = brow * 256 + ((q ^ (brow & 7)) << 4);
        }
    }

    float se[2][4] = {{0,0,0,0},{0,0,0,0}};
    float ps[2][4] = {{0,0,0,0},{0,0,0,0}};
    float sd[2][4] = {{0,0,0,0},{0,0,0,0}};
    const int tdiag = rb >> 1;

    for (int t = 0; t < 16; ++t) {
        const int cur = t & 1;
        if (t < 15) {            // T3-min: issue next-tile staging before compute
            #pragma unroll
            for (int c = 0; c < 8; ++c) {
                GLOAD16(gsrc[c], (char*)(&Bt[cur ^ 1][0]) + (c * 4 + w) * 1024);
                gsrc[c] += 128 * DDIM;
            }
        }
        const char* base = (const char*)(&Bt[cur][0]);

        f32x4 acc[2][4];
        #pragma unroll
        for (int fr = 0; fr < 2; ++fr)
            #pragma unroll
            for (int fc = 0; fc < 4; ++fc)
                acc[fr][fc] = (f32x4){0.f, 0.f, 0.f, 0.f};

        #pragma unroll
        for (int ks = 0; ks < 4; ++ks) {
            bf16x8 bfrag[4];
            #pragma unroll
            for (int fc = 0; fc < 4; ++fc)
                bfrag[fc] = *reinterpret_cast<const bf16x8*>(base + boff[fc][ks]);
            #pragma unroll
            for (int fr = 0; fr < 2; ++fr)
                #pragma unroll
                for (int fc = 0; fc < 4; ++fc)
                    acc[fr][fc] = __builtin_amdgcn_mfma_f32_16x16x32_bf16(
                        afrag[fr][ks], bfrag[fc], acc[fr][fc], 0, 0, 0);
        }

        // ---- epilogue: 2-inst exp-sum + 3-inst masked positive sum (no diag logic)
        const int m0 = t * 128;
        #pragma unroll
        for (int fc = 0; fc < 4; ++fc) {
            const int m = m0 + wcol * 64 + fc * 16 + (lane & 15);
            const int lm = slab[m & 1023];
            #pragma unroll
            for (int fr = 0; fr < 2; ++fr)
                #pragma unroll
                for (int j = 0; j < 4; ++j) {
                    const float val = acc[fr][fc][j];
                    se[fr][j] += exp2f(fmaf(val, KL2E, NC2));
                    ps[fr][j] += (lm == rowlab[fr][j]) ? val : 0.f;
                }
        }
        // diag extraction: exactly one tile per block, uniform branch
        if (t == tdiag) {
            #pragma unroll
            for (int fc = 0; fc < 4; ++fc) {
                const int m = m0 + wcol * 64 + fc * 16 + (lane & 15);
                #pragma unroll
                for (int fr = 0; fr < 2; ++fr)
                    #pragma unroll
                    for (int j = 0; j < 4; ++j)
                        if (m == rown[fr][j]) sd[fr][j] = acc[fr][fc][j];
            }
        }
        __syncthreads();   // drains vmcnt: staged tile ready; all reads of Bt[cur] done
    }

    // ---- per-row reduce (16 col-lanes) then cross-wave combine
    #pragma unroll
    for (int fr = 0; fr < 2; ++fr)
        #pragma unroll
        for (int j = 0; j < 4; ++j) {
            float s = se[fr][j], P = ps[fr][j], D = sd[fr][j];
            #pragma unroll
            for (int o = 1; o < 16; o <<= 1) {
                s += __shfl_xor(s, o);
                P += __shfl_xor(P, o);
                D += __shfl_xor(D, o);
            }
            if ((lane & 15) == 0) {
                const int r = wrow * 32 + fr * 16 + ((lane >> 4) << 2) + j;
                red_se[wcol][r] = s; red_ps[wcol][r] = P; red_sd[wcol][r] = D;
            }
        }
    __syncthreads();
    if (tid < 64) {
        const int gn = b * NROWS + n0 + tid;
        rsum_ws[gn] = red_se[0][tid] + red_se[1][tid];
        ps_ws[gn]   = red_ps[0][tid] + red_ps[1][tid];
        sd_ws[gn]   = red_sd[0][tid] + red_sd[1][tid];
    }
}

// ---------------- K3: finalize — per-row loss from (rsum, ps, sd) + label histogram
__global__ __launch_bounds__(256) void finalize_kernel(
    const int* __restrict__ labels,
    const float* __restrict__ rsum_ws, const float* __restrict__ ps_ws,
    const float* __restrict__ sd_ws, float* __restrict__ out)
{
    __shared__ int cnt_s[64];
    __shared__ float wred[4];
    const int tid = threadIdx.x, lane = tid & 63, wv = tid >> 6;
    const int gid = blockIdx.x * 256 + tid;      // 0..32767 (128 blocks)
    const int b = gid >> 11, n = gid & 2047;
    const int* lb = labels + b * 1024;

    if (tid < 64) cnt_s[tid] = 0;
    __syncthreads();
    #pragma unroll
    for (int k = 0; k < 4; ++k) atomicAdd(&cnt_s[lb[tid * 4 + k]], 1);
    __syncthreads();

    const int l = lb[n & 1023];
    const float poscnt = (float)(2 * cnt_s[l] - 1);   // >=1 (other view always positive)
    const float D  = sd_ws[gid];                       // exact MFMA self-dot
    const float P  = ps_ws[gid] - D;                   // exclude diagonal
    const float rs = rsum_ws[gid] - exp2f(fmaf(D, KL2E, NC2));
    float mlpp = P * TEMP_INV / poscnt - TEMP_INV - __logf(rs);

    #pragma unroll
    for (int o = 1; o < 64; o <<= 1) mlpp += __shfl_xor(mlpp, o);
    if (lane == 0) wred[wv] = mlpp;
    __syncthreads();
    if (tid == 0)
        atomicAdd(out, -(wred[0] + wred[1] + wred[2] + wred[3]) * (1.0f / 32768.0f));
}

extern "C" void kernel_launch(void* const* d_in, const int* in_sizes, int n_in,
                              void* d_out, int out_size, void* d_ws, size_t ws_size,
                              hipStream_t stream) {
    const float* feat = (const float*)d_in[0];
    const int* labels = (const int*)d_in[1];
    float* out = (float*)d_out;

    char* ws = (char*)d_ws;
    __hip_bfloat16* contrast = (__hip_bfloat16*)ws;            // 8,388,608 B
    float* rsum_ws = (float*)(ws + 8388608);                   // 131,072 B
    float* ps_ws   = (float*)(ws + 8519680);                   // 131,072 B
    float* sd_ws   = (float*)(ws + 8650752);                   // 131,072 B

    hipMemsetAsync(d_out, 0, sizeof(float), stream);
    cast_reorder_kernel<<<4096, 256, 0, stream>>>(feat, contrast);
    supcon_main_kernel<<<512, 256, 0, stream>>>(contrast, labels, rsum_ws, ps_ws, sd_ws);
    finalize_kernel<<<128, 256, 0, stream>>>(labels, rsum_ws, ps_ws, sd_ws, out);
}